// Round 3
// baseline (546.900 us; speedup 1.0000x reference)
//
#include <hip/hip_runtime.h>
#include <hip/hip_cooperative_groups.h>

namespace cg = cooperative_groups;

// HMM trajectory forward, rank-1+diag rewrite.
// R7: LINEAR (unnormalized) chunk recurrence: P <- E1*S + E2*P, S = sum(P*EB).
// Power-of-2 renorm every CH steps (exact); chunk log telescopes to two log2s.
// R8/R9: parallel length-aware pre-gather of chosen(B,T,64); private ws slots.
// R10: single cooperative kernel: gather -> grid.sync -> chunk recurrence ->
//      grid.sync -> reduce. Removes 2 dispatch gaps + reduce launch; chosen
//      stays L2-hot. CLEN 64->32 (2x time-parallelism; grid 1024 blocks also
//      feeds the gather phase). Fallback to 3-kernel path if coop launch or
//      ws_size fails.

#define CH   8     // register pipeline depth (double-buffered); renorm cadence
#define WARM 16    // warm-up steps (direction convergence)
#define CLEN 32    // accumulated steps per chunk
#define NB   64

template <int CTRL, int RMASK>
__device__ __forceinline__ float dpp_add(float x) {
    int yi = __builtin_amdgcn_update_dpp(
        0, __builtin_bit_cast(int, x), CTRL, RMASK, 0xf, true);
    return x + __builtin_bit_cast(float, yi);
}

// sum over 64 lanes -> wave-uniform scalar
__device__ __forceinline__ float wave_sum64(float x) {
    x = dpp_add<0x111, 0xf>(x);   // row_shr:1
    x = dpp_add<0x112, 0xf>(x);   // row_shr:2
    x = dpp_add<0x114, 0xf>(x);   // row_shr:4
    x = dpp_add<0x118, 0xf>(x);   // row_shr:8
    x = dpp_add<0x142, 0xa>(x);   // row_bcast:15 -> rows 1,3
    x = dpp_add<0x143, 0xc>(x);   // row_bcast:31 -> row 3
    return __builtin_bit_cast(float,
        __builtin_amdgcn_readlane(__builtin_bit_cast(int, x), 63));
}

// ---- phase helpers (shared by fused and fallback kernels) -------------------

// Gather chosen[b,t,k] = act[b,t,k,actions[b,t]] for t < L_b.
// wave-per-row mapping: one wave = one (b,t) row (lane = k), unroll 4 rows.
__device__ __forceinline__ void gather_phase(
    const float* __restrict__ act, const int* __restrict__ actions,
    const int* __restrict__ lengths, float* __restrict__ chosen,
    int B, int T, int A, int waveId, int nWaves, int lane)
{
    const int nrows = B * T;
    for (int r0 = waveId * 4; r0 < nrows; r0 += nWaves * 4) {
        float  v[4]; size_t dst[4]; bool ok[4];
#pragma unroll
        for (int u = 0; u < 4; ++u) {
            const int r = r0 + u;
            ok[u] = false;
            if (r < nrows) {
                const int b = r / T;
                const int t = r - b * T;
                if (t < lengths[b]) {               // fwd never reads t >= L
                    const int a = actions[r];       // wave-uniform
                    v[u] = __builtin_nontemporal_load(
                        act + (((size_t)b * (T + 1) + t) * NB + lane) * A + a);
                    dst[u] = (size_t)r * NB + lane;
                    ok[u] = true;
                }
            }
        }
#pragma unroll
        for (int u = 0; u < 4; ++u)
            if (ok[u]) chosen[dst[u]] = v[u];
    }
}

// One (bi, c) chunk of the recurrence; writes ws[bi*NC + c].
template <bool PG>
__device__ __forceinline__ void fwd_chunk(
    const float* __restrict__ stop, const float* __restrict__ start,
    const float* __restrict__ act, const int* __restrict__ actions,
    const int* __restrict__ lengths, const float* __restrict__ chosen,
    float* __restrict__ ws, int T, int A, int NC, int bi, int c, int lane)
{
    const int Tp1  = T + 1;
    const int rowA = NB * A;

    const int L = lengths[bi];                     // block-uniform
    const int a = 1 + c * CLEN;                    // first accumulated step
    const int cstar = (L >= 2) ? ((L - 2) / CLEN) : 0;  // terminal chunk
    if (c > cstar) return;

    const int t_end = min(L, a + CLEN);            // exclusive
    const int t0    = (c == 0) ? 1 : (a - WARM);
    const int n     = t_end - t0;                  // 0 possible (L==1, c==0)
    const int nwarm = a - t0;                      // 0 or WARM

    const float* stopB  = stop  + (size_t)bi * Tp1 * NB * 2;
    const float* startB = start + (size_t)bi * Tp1 * NB;
    const float* actB   = act   + (size_t)bi * Tp1 * NB * A;
    const int*   actsB  = actions + (size_t)bi * T;

    // Fallback path only: stage act element-offsets, clamped to t_end-1.
    __shared__ int offL[CLEN + WARM + CH];
    if constexpr (!PG) {
        for (int i = lane; i < n + CH; i += 64) {
            const int tt = min(t0 + i, t_end - 1);
            offL[i] = tt * rowA + actsB[tt];
        }
    }

    float p = (c == 0) ? ((lane == 0) ? 1.0f : 0.0f) : 1.0f;
    float slast   = 1.0f;   // last computed S (kept scale-consistent)
    float warmcap = 0.0f;   // log2 S^u at warm boundary (incl. shifts)
    float Eshift  = 0.0f;   // total pow2 exponent removed so far

    const float* spL = stopB  + (size_t)t0 * (NB * 2) + lane * 2;
    const float* stL = startB + (size_t)t0 * NB + lane;
    const float* chL = PG ? (chosen + ((size_t)bi * T + t0) * NB + lane)
                          : (const float*)nullptr;
    const int laneA = lane * A;

    float bB[2][CH], bO[2][CH], bS[2][CH], bC[2][CH];

#define LOADF(SL, j) do {                                                    \
    const float* sp  = spL + (size_t)(j) * (CH * NB * 2);                    \
    const float* st2 = stL + (size_t)(j) * (CH * NB);                        \
    _Pragma("unroll")                                                        \
    for (int i = 0; i < CH; ++i) {                                           \
        if constexpr (PG)                                                    \
            bC[SL][i] = chL[((size_t)((j) * CH + i)) * NB];                  \
        else                                                                 \
            bC[SL][i] = actB[offL[(j) * CH + i] + laneA];                    \
        const float2 so = *(const float2*)(sp + i * (NB * 2));               \
        bB[SL][i] = so.x;                                                    \
        bO[SL][i] = so.y;                                                    \
        bS[SL][i] = st2[i * NB];                                             \
    } } while (0)

#define LOADC(SL, j) do {                                                    \
    _Pragma("unroll")                                                        \
    for (int i = 0; i < CH; ++i) {                                           \
        const int tt = min(t0 + (j) * CH + i, t_end - 1);                    \
        if constexpr (PG)                                                    \
            bC[SL][i] = chosen[((size_t)bi * T + tt) * NB + lane];           \
        else                                                                 \
            bC[SL][i] = actB[offL[(j) * CH + i] + laneA];                    \
        const float2 so = *(const float2*)(stopB + (size_t)tt * (NB * 2)     \
                                           + lane * 2);                      \
        bB[SL][i] = so.x;                                                    \
        bO[SL][i] = so.y;                                                    \
        bS[SL][i] = startB[(size_t)tt * NB + lane];                          \
    } } while (0)

#define LOAD(SL, j) do {                                                     \
    if (((j) + 1) * CH <= n) LOADF(SL, j); else LOADC(SL, j); } while (0)

#define COMPUTE(SL, j) do {                                                  \
    _Pragma("unroll")                                                        \
    for (int i = 0; i < CH; ++i) {                                           \
        if ((j) * CH + i < n) {                                              \
            const float e1 = __expf(bC[SL][i] + bS[SL][i]);                  \
            const float e2 = __expf(bC[SL][i] + bO[SL][i]);                  \
            const float eb = __expf(bB[SL][i]);                              \
            const float q  = e2 * p;             /* overlaps reduction */    \
            const float s  = wave_sum64(p * eb);                             \
            slast = s;                                                       \
            if ((j) * CH + i == nwarm - 1)                                   \
                warmcap = __log2f(s) + Eshift;                               \
            p = fmaf(e1, s, q);                                              \
        }                                                                    \
    }                                                                        \
    /* exact pow2 renorm (once per CH steps) */                              \
    {                                                                        \
        const unsigned sb = __builtin_bit_cast(unsigned, slast);             \
        const int ef = (int)(sb >> 23);          /* biased exponent */       \
        const float sc = __builtin_bit_cast(float,                           \
                             (unsigned)(254 - ef) << 23);   /* 2^-(ef-127) */\
        p *= sc;                                                             \
        slast *= sc;                                                         \
        Eshift += (float)(ef - 127);                                         \
    } } while (0)

    const int nch = (n + CH - 1) / CH;
    if (n > 0) {
        int j = 0;
        LOAD(0, 0);
        while (true) {
            if (j + 1 < nch) LOAD(1, j + 1);
            COMPUTE(0, j);
            ++j; if (j >= nch) break;
            if (j + 1 < nch) LOAD(0, j + 1);
            COMPUTE(1, j);
            ++j; if (j >= nch) break;
        }
    }

    float C2;
    if (c == cstar) {   // terminal: log2(sum_k P[k] * exp(beta_stop[L,k]))
        const float bl = stopB[(size_t)L * (NB * 2) + lane * 2];
        const float s  = wave_sum64(p * __expf(bl));
        C2 = __log2f(s) + Eshift - warmcap;
    } else {
        C2 = __log2f(slast) + Eshift - warmcap;
    }

    // Private slot per (b, c): every slot the reducer reads (c <= cstar(L_b))
    // is written by exactly one block in the same invocation.
    if (lane == 0)
        ws[(size_t)bi * NC + c] = C2;

#undef LOADF
#undef LOADC
#undef LOAD
#undef COMPUTE
}

__device__ __forceinline__ void reduce_phase(
    const float* __restrict__ ws, const int* __restrict__ lengths,
    float* __restrict__ out, int B, int NC, int lane)
{
    float acc = 0.0f;
    for (int b = lane; b < B; b += 64) {
        const int L = lengths[b];
        const int cs = (L >= 2) ? ((L - 2) / CLEN) : 0;
        float s = 0.0f;
        for (int c = 0; c <= cs; ++c)
            s += ws[(size_t)b * NC + c];
        acc += s;
    }
    const float tot = wave_sum64(acc);
    if (lane == 0)
        out[0] = -0.69314718055994531f * tot;
}

// ---- fused cooperative kernel ----------------------------------------------

__global__ __launch_bounds__(64)
void hmm_fused(const float* __restrict__ stop, const float* __restrict__ start,
               const float* __restrict__ act, const int* __restrict__ actions,
               const int* __restrict__ lengths, float* __restrict__ chosen,
               float* __restrict__ ws, float* __restrict__ out,
               int T, int A, int NC, int B)
{
    const int lane   = threadIdx.x;
    const int waveId = blockIdx.x * gridDim.y + blockIdx.y;
    const int nWaves = gridDim.x * gridDim.y;

    gather_phase(act, actions, lengths, chosen, B, T, A, waveId, nWaves, lane);
    __threadfence();
    cg::this_grid().sync();

    fwd_chunk<true>(stop, start, act, actions, lengths, chosen, ws,
                    T, A, NC, blockIdx.x, blockIdx.y, lane);
    __threadfence();
    cg::this_grid().sync();

    if (blockIdx.x == 0 && blockIdx.y == 0)
        reduce_phase(ws, lengths, out, B, NC, lane);
}

// ---- fallback kernels (3-dispatch path) ------------------------------------

__global__ __launch_bounds__(256)
void hmm_gather(const float* __restrict__ act, const int* __restrict__ actions,
                const int* __restrict__ lengths, float* __restrict__ chosen,
                int T, int A)
{
    const int b = blockIdx.y;
    const int L = lengths[b];
    const int i = blockIdx.x * 256 + threadIdx.x;   // t*64 + k
    const int t = i >> 6;
    if (t >= T || t >= L) return;
    const int k = i & 63;
    const int a = actions[(size_t)b * T + t];
    chosen[((size_t)b * T + t) * 64 + k] =
        act[(((size_t)b * (T + 1) + t) * 64 + k) * A + a];
}

template <bool PG>
__global__ __launch_bounds__(64)
void hmm_fwd(const float* __restrict__ stop, const float* __restrict__ start,
             const float* __restrict__ act, const int* __restrict__ actions,
             const int* __restrict__ lengths, const float* __restrict__ chosen,
             float* __restrict__ ws, int T, int A, int NC)
{
    fwd_chunk<PG>(stop, start, act, actions, lengths, chosen, ws,
                  T, A, NC, blockIdx.x, blockIdx.y, threadIdx.x);
}

__global__ __launch_bounds__(64)
void hmm_reduce(const float* __restrict__ ws, const int* __restrict__ lengths,
                float* __restrict__ out, int B, int NC)
{
    reduce_phase(ws, lengths, out, B, NC, threadIdx.x);
}

// ---- launch ----------------------------------------------------------------

extern "C" void kernel_launch(void* const* d_in, const int* in_sizes, int n_in,
                              void* d_out, int out_size, void* d_ws, size_t ws_size,
                              hipStream_t stream)
{
    const float* stop    = (const float*)d_in[0];
    const float* start   = (const float*)d_in[1];
    const float* act     = (const float*)d_in[2];
    const int*   actions = (const int*)d_in[3];
    const int*   lengths = (const int*)d_in[4];
    float* out = (float*)d_out;
    float* ws  = (float*)d_ws;

    const int B   = in_sizes[4];
    const int T   = in_sizes[3] / B;
    const int Tp1 = T + 1;
    const int A   = in_sizes[2] / (B * Tp1 * 64);

    int NC = (T - 1 + CLEN - 1) / CLEN;   // chunks covering t=1..T-1
    if (NC < 1) NC = 1;

    // ws layout: [B*NC partial C2][pad to 64 floats][B*T*64 chosen]
    const size_t partial_floats = (((size_t)B * NC) + 63) & ~(size_t)63;
    const size_t chosen_bytes   = (size_t)B * T * 64 * sizeof(float);
    const bool   pg = (ws_size >= partial_floats * sizeof(float) + chosen_bytes);
    float* chosen = ws + partial_floats;

    bool done = false;
    if (pg) {
        void* args[] = {
            (void*)&stop, (void*)&start, (void*)&act, (void*)&actions,
            (void*)&lengths, (void*)&chosen, (void*)&ws, (void*)&out,
            (void*)&T, (void*)&A, (void*)&NC, (void*)&B };
        const hipError_t e = hipLaunchCooperativeKernel(
            reinterpret_cast<const void*>(hmm_fused),
            dim3(B, NC), dim3(64), args, 0, stream);
        done = (e == hipSuccess);
    }

    if (!done) {
        if (pg) {
            hmm_gather<<<dim3((T * 64 + 255) / 256, B), dim3(256), 0, stream>>>(
                act, actions, lengths, chosen, T, A);
            hmm_fwd<true><<<dim3(B, NC), dim3(64), 0, stream>>>(
                stop, start, act, actions, lengths, chosen, ws, T, A, NC);
        } else {
            hmm_fwd<false><<<dim3(B, NC), dim3(64), 0, stream>>>(
                stop, start, act, actions, lengths, nullptr, ws, T, A, NC);
        }
        hmm_reduce<<<dim3(1), dim3(64), 0, stream>>>(ws, lengths, out, B, NC);
    }
}

// Round 4
// 221.300 us; speedup vs baseline: 2.4713x; 2.4713x over previous
//
#include <hip/hip_runtime.h>

// HMM trajectory forward, rank-1+diag rewrite.
// R7: LINEAR (unnormalized) chunk recurrence: P <- E1*S + E2*P, S = sum(P*EB).
// Power-of-2 renorm every CH steps (exact); chunk log telescopes to two log2s.
// R10 post-mortem: cooperative fusion = 355us (grid.sync spin + NT loads);
// separate gather kernel (R8/R9) also net-negative vs in-kernel gather.
// R11: back to 2-dispatch in-kernel-gather structure (the 218us session
// baseline) with two latency fixes:
//   - CLEN 64->32: 1024 blocks (2x MLP), 48-step chains (was 80).
//   - triple-buffered CH=8 pipeline: 2 batches in flight (~530ns issue-ahead
//     > ~400ns HBM latency) removes the per-batch stall bubble.
//   CH stays 8: renorm cadence >8 underflows p to denormals (e^{-7*16}).
// No memset, no atomics: fwd writes private slot ws[bi*NC+c]; reduce
// recomputes cstar(L_b) and reads exactly the slots written this iteration.

#define CH   8     // register pipeline depth; renorm cadence (numeric bound)
#define WARM 16    // warm-up steps (direction convergence)
#define CLEN 32    // accumulated steps per chunk
#define NB   64

template <int CTRL, int RMASK>
__device__ __forceinline__ float dpp_add(float x) {
    int yi = __builtin_amdgcn_update_dpp(
        0, __builtin_bit_cast(int, x), CTRL, RMASK, 0xf, true);
    return x + __builtin_bit_cast(float, yi);
}

// sum over 64 lanes -> wave-uniform scalar
__device__ __forceinline__ float wave_sum64(float x) {
    x = dpp_add<0x111, 0xf>(x);   // row_shr:1
    x = dpp_add<0x112, 0xf>(x);   // row_shr:2
    x = dpp_add<0x114, 0xf>(x);   // row_shr:4
    x = dpp_add<0x118, 0xf>(x);   // row_shr:8
    x = dpp_add<0x142, 0xa>(x);   // row_bcast:15 -> rows 1,3
    x = dpp_add<0x143, 0xc>(x);   // row_bcast:31 -> row 3
    return __builtin_bit_cast(float,
        __builtin_amdgcn_readlane(__builtin_bit_cast(int, x), 63));
}

__global__ __launch_bounds__(64)
void hmm_fwd(const float* __restrict__ stop,     // (B, T+1, 64, 2)
             const float* __restrict__ start,    // (B, T+1, 64)
             const float* __restrict__ act,      // (B, T+1, 64, A)
             const int*   __restrict__ actions,  // (B, T)
             const int*   __restrict__ lengths,  // (B,)
             float* __restrict__ ws,             // (B*NC) partial C2 (log2)
             int T, int A, int NC)
{
    const int bi   = blockIdx.x;
    const int c    = blockIdx.y;
    const int lane = threadIdx.x;
    const int Tp1  = T + 1;
    const int rowA = NB * A;

    const int L = lengths[bi];                     // block-uniform
    const int a = 1 + c * CLEN;                    // first accumulated step
    const int cstar = (L >= 2) ? ((L - 2) / CLEN) : 0;  // terminal chunk
    if (c > cstar) return;

    const int t_end = min(L, a + CLEN);            // exclusive
    const int t0    = (c == 0) ? 1 : (a - WARM);
    const int n     = t_end - t0;                  // 0 possible (L==1, c==0)
    const int nwarm = a - t0;                      // 0 or WARM

    const float* stopB  = stop  + (size_t)bi * Tp1 * NB * 2;
    const float* startB = start + (size_t)bi * Tp1 * NB;
    const float* actB   = act   + (size_t)bi * Tp1 * NB * A;
    const int*   actsB  = actions + (size_t)bi * T;

    // Stage act element-offsets (t*rowA + action[t]), clamped to t_end-1.
    // Single-wave block: LDS write->read needs only lgkmcnt (no barrier).
    __shared__ int offL[CLEN + WARM + CH];
    for (int i = lane; i < n + CH; i += 64) {
        const int tt = min(t0 + i, t_end - 1);
        offL[i] = tt * rowA + actsB[tt];
    }

    float p = (c == 0) ? ((lane == 0) ? 1.0f : 0.0f) : 1.0f;
    float slast   = 1.0f;   // last computed S (kept scale-consistent)
    float warmcap = 0.0f;   // log2 S^u at warm boundary (incl. shifts)
    float Eshift  = 0.0f;   // total pow2 exponent removed so far

    const float* spL = stopB  + (size_t)t0 * (NB * 2) + lane * 2;
    const float* stL = startB + (size_t)t0 * NB + lane;
    const int laneA = lane * A;

    float bB[3][CH], bO[3][CH], bS[3][CH], bC[3][CH];   // triple-buffered

#define LOADF(SL, j) do {                                                    \
    const float* sp  = spL + (size_t)(j) * (CH * NB * 2);                    \
    const float* st2 = stL + (size_t)(j) * (CH * NB);                        \
    _Pragma("unroll")                                                        \
    for (int i = 0; i < CH; ++i) {                                           \
        bC[SL][i] = actB[offL[(j) * CH + i] + laneA];                        \
        const float2 so = *(const float2*)(sp + i * (NB * 2));               \
        bB[SL][i] = so.x;                                                    \
        bO[SL][i] = so.y;                                                    \
        bS[SL][i] = st2[i * NB];                                             \
    } } while (0)

#define LOADC(SL, j) do {                                                    \
    _Pragma("unroll")                                                        \
    for (int i = 0; i < CH; ++i) {                                           \
        bC[SL][i] = actB[offL[(j) * CH + i] + laneA];                        \
        const int tt = min(t0 + (j) * CH + i, t_end - 1);                    \
        const float2 so = *(const float2*)(stopB + (size_t)tt * (NB * 2)     \
                                           + lane * 2);                      \
        bB[SL][i] = so.x;                                                    \
        bO[SL][i] = so.y;                                                    \
        bS[SL][i] = startB[(size_t)tt * NB + lane];                          \
    } } while (0)

#define LOAD(SL, j) do {                                                     \
    if (((j) + 1) * CH <= n) LOADF(SL, j); else LOADC(SL, j); } while (0)

#define COMPUTE(SL, j) do {                                                  \
    _Pragma("unroll")                                                        \
    for (int i = 0; i < CH; ++i) {                                           \
        if ((j) * CH + i < n) {                                              \
            const float e1 = __expf(bC[SL][i] + bS[SL][i]);                  \
            const float e2 = __expf(bC[SL][i] + bO[SL][i]);                  \
            const float eb = __expf(bB[SL][i]);                              \
            const float q  = e2 * p;             /* overlaps reduction */    \
            const float s  = wave_sum64(p * eb);                             \
            slast = s;                                                       \
            if ((j) * CH + i == nwarm - 1)                                   \
                warmcap = __log2f(s) + Eshift;                               \
            p = fmaf(e1, s, q);                                              \
        }                                                                    \
    }                                                                        \
    /* exact pow2 renorm (once per CH steps) */                              \
    {                                                                        \
        const unsigned sb = __builtin_bit_cast(unsigned, slast);             \
        const int ef = (int)(sb >> 23);          /* biased exponent */       \
        const float sc = __builtin_bit_cast(float,                           \
                             (unsigned)(254 - ef) << 23);   /* 2^-(ef-127) */\
        p *= sc;                                                             \
        slast *= sc;                                                         \
        Eshift += (float)(ef - 127);                                         \
    } } while (0)

    const int nch = (n + CH - 1) / CH;
    if (n > 0) {
        LOAD(0, 0);
        if (nch > 1) LOAD(1, 1);
        int j = 0;
        while (true) {
            if (j + 2 < nch) LOAD(2, j + 2);
            COMPUTE(0, j);
            ++j; if (j >= nch) break;
            if (j + 2 < nch) LOAD(0, j + 2);
            COMPUTE(1, j);
            ++j; if (j >= nch) break;
            if (j + 2 < nch) LOAD(1, j + 2);
            COMPUTE(2, j);
            ++j; if (j >= nch) break;
        }
    }

    float C2;
    if (c == cstar) {   // terminal: log2(sum_k P[k] * exp(beta_stop[L,k]))
        const float bl = stopB[(size_t)L * (NB * 2) + lane * 2];
        const float s  = wave_sum64(p * __expf(bl));
        C2 = __log2f(s) + Eshift - warmcap;
    } else {
        C2 = __log2f(slast) + Eshift - warmcap;
    }

    // Private slot per (b, c): every slot the reducer reads (c <= cstar(L_b))
    // is written by exactly one block in this same launch.
    if (lane == 0)
        ws[(size_t)bi * NC + c] = C2;

#undef LOADF
#undef LOADC
#undef LOAD
#undef COMPUTE
}

__global__ __launch_bounds__(64)
void hmm_reduce(const float* __restrict__ ws,       // (B, NC) chunk C2 (log2)
                const int*   __restrict__ lengths,  // (B,)
                float* __restrict__ out, int B, int NC)
{
    const int lane = threadIdx.x;
    float acc = 0.0f;
    for (int b = lane; b < B; b += 64) {
        const int L = lengths[b];
        const int cs = (L >= 2) ? ((L - 2) / CLEN) : 0;
        float s = 0.0f;
        for (int c = 0; c <= cs; ++c)
            s += ws[(size_t)b * NC + c];
        acc += s;
    }
    const float tot = wave_sum64(acc);
    if (lane == 0)
        out[0] = -0.69314718055994531f * tot;
}

extern "C" void kernel_launch(void* const* d_in, const int* in_sizes, int n_in,
                              void* d_out, int out_size, void* d_ws, size_t ws_size,
                              hipStream_t stream)
{
    const float* stop    = (const float*)d_in[0];
    const float* start   = (const float*)d_in[1];
    const float* act     = (const float*)d_in[2];
    const int*   actions = (const int*)d_in[3];
    const int*   lengths = (const int*)d_in[4];
    float* out = (float*)d_out;
    float* ws  = (float*)d_ws;

    const int B   = in_sizes[4];
    const int T   = in_sizes[3] / B;
    const int Tp1 = T + 1;
    const int A   = in_sizes[2] / (B * Tp1 * 64);

    int NC = (T - 1 + CLEN - 1) / CLEN;   // chunks covering t=1..T-1
    if (NC < 1) NC = 1;

    hmm_fwd<<<dim3(B, NC), dim3(64), 0, stream>>>(
        stop, start, act, actions, lengths, ws, T, A, NC);
    hmm_reduce<<<dim3(1), dim3(64), 0, stream>>>(ws, lengths, out, B, NC);
}

// Round 5
// 218.708 us; speedup vs baseline: 2.5006x; 1.0119x over previous
//
#include <hip/hip_runtime.h>

// HMM trajectory forward, rank-1+diag rewrite.
// R7: LINEAR (unnormalized) chunk recurrence: P <- E1*S + E2*P, S = sum(P*EB).
// Power-of-2 renorm every CH steps (exact); chunk log telescopes to two log2s.
// R10 post-mortem: cooperative fusion = 355us. R11 post-mortem: CLEN=32 cost
// ~3us (warm re-read overhead 50% vs 25%); parallelism gain nil (BW-bound).
// R12: CLEN back to 64 (min warm traffic), KEEP triple-buffered CH=8 pipeline
// (2 batches in flight covers HBM latency), and clamp offL staging with T
// instead of t_end (drops the lengths->staging dependency: act loads issue
// from instruction 0; overshoot rows are discarded by the i<n compute guard).
// No memset, no atomics: fwd writes private slot ws[bi*NC+c]; reduce
// recomputes cstar(L_b) and reads exactly the slots written this iteration.

#define CH   8     // register pipeline depth; renorm cadence (numeric bound)
#define WARM 16    // warm-up steps (direction convergence)
#define CLEN 64    // accumulated steps per chunk
#define NB   64

template <int CTRL, int RMASK>
__device__ __forceinline__ float dpp_add(float x) {
    int yi = __builtin_amdgcn_update_dpp(
        0, __builtin_bit_cast(int, x), CTRL, RMASK, 0xf, true);
    return x + __builtin_bit_cast(float, yi);
}

// sum over 64 lanes -> wave-uniform scalar
__device__ __forceinline__ float wave_sum64(float x) {
    x = dpp_add<0x111, 0xf>(x);   // row_shr:1
    x = dpp_add<0x112, 0xf>(x);   // row_shr:2
    x = dpp_add<0x114, 0xf>(x);   // row_shr:4
    x = dpp_add<0x118, 0xf>(x);   // row_shr:8
    x = dpp_add<0x142, 0xa>(x);   // row_bcast:15 -> rows 1,3
    x = dpp_add<0x143, 0xc>(x);   // row_bcast:31 -> row 3
    return __builtin_bit_cast(float,
        __builtin_amdgcn_readlane(__builtin_bit_cast(int, x), 63));
}

__global__ __launch_bounds__(64)
void hmm_fwd(const float* __restrict__ stop,     // (B, T+1, 64, 2)
             const float* __restrict__ start,    // (B, T+1, 64)
             const float* __restrict__ act,      // (B, T+1, 64, A)
             const int*   __restrict__ actions,  // (B, T)
             const int*   __restrict__ lengths,  // (B,)
             float* __restrict__ ws,             // (B*NC) partial C2 (log2)
             int T, int A, int NC)
{
    const int bi   = blockIdx.x;
    const int c    = blockIdx.y;
    const int lane = threadIdx.x;
    const int Tp1  = T + 1;
    const int rowA = NB * A;

    const int a  = 1 + c * CLEN;                   // first accumulated step
    const int t0 = (c == 0) ? 1 : (a - WARM);

    const float* stopB  = stop  + (size_t)bi * Tp1 * NB * 2;
    const float* startB = start + (size_t)bi * Tp1 * NB;
    const float* actB   = act   + (size_t)bi * Tp1 * NB * A;
    const int*   actsB  = actions + (size_t)bi * T;

    // Stage act element-offsets (t*rowA + action[t]); clamp with T-1 (always
    // in-bounds, independent of lengths -> issues immediately at kernel start;
    // overshoot rows beyond n are loaded but discarded by the i<n guard).
    // Single-wave block: LDS write->read needs only lgkmcnt (no barrier).
    __shared__ int offL[CLEN + WARM + CH];
    for (int i = lane; i < CLEN + WARM + CH; i += 64) {
        const int tt = min(t0 + i, T - 1);
        offL[i] = tt * rowA + actsB[tt];
    }

    const int L = lengths[bi];                     // block-uniform
    const int cstar = (L >= 2) ? ((L - 2) / CLEN) : 0;  // terminal chunk
    if (c > cstar) return;

    const int t_end = min(L, a + CLEN);            // exclusive
    const int n     = t_end - t0;                  // 0 possible (L==1, c==0)
    const int nwarm = a - t0;                      // 0 or WARM

    float p = (c == 0) ? ((lane == 0) ? 1.0f : 0.0f) : 1.0f;
    float slast   = 1.0f;   // last computed S (kept scale-consistent)
    float warmcap = 0.0f;   // log2 S^u at warm boundary (incl. shifts)
    float Eshift  = 0.0f;   // total pow2 exponent removed so far

    const float* spL = stopB  + (size_t)t0 * (NB * 2) + lane * 2;
    const float* stL = startB + (size_t)t0 * NB + lane;
    const int laneA = lane * A;

    float bB[3][CH], bO[3][CH], bS[3][CH], bC[3][CH];   // triple-buffered

#define LOADF(SL, j) do {                                                    \
    const float* sp  = spL + (size_t)(j) * (CH * NB * 2);                    \
    const float* st2 = stL + (size_t)(j) * (CH * NB);                        \
    _Pragma("unroll")                                                        \
    for (int i = 0; i < CH; ++i) {                                           \
        bC[SL][i] = actB[offL[(j) * CH + i] + laneA];                        \
        const float2 so = *(const float2*)(sp + i * (NB * 2));               \
        bB[SL][i] = so.x;                                                    \
        bO[SL][i] = so.y;                                                    \
        bS[SL][i] = st2[i * NB];                                             \
    } } while (0)

#define LOADC(SL, j) do {                                                    \
    _Pragma("unroll")                                                        \
    for (int i = 0; i < CH; ++i) {                                           \
        bC[SL][i] = actB[offL[(j) * CH + i] + laneA];                        \
        const int tt = min(t0 + (j) * CH + i, T);   /* rows 0..T valid */    \
        const float2 so = *(const float2*)(stopB + (size_t)tt * (NB * 2)     \
                                           + lane * 2);                      \
        bB[SL][i] = so.x;                                                    \
        bO[SL][i] = so.y;                                                    \
        bS[SL][i] = startB[(size_t)tt * NB + lane];                          \
    } } while (0)

#define LOAD(SL, j) do {                                                     \
    if (((j) + 1) * CH <= n) LOADF(SL, j); else LOADC(SL, j); } while (0)

#define COMPUTE(SL, j) do {                                                  \
    _Pragma("unroll")                                                        \
    for (int i = 0; i < CH; ++i) {                                           \
        if ((j) * CH + i < n) {                                              \
            const float e1 = __expf(bC[SL][i] + bS[SL][i]);                  \
            const float e2 = __expf(bC[SL][i] + bO[SL][i]);                  \
            const float eb = __expf(bB[SL][i]);                              \
            const float q  = e2 * p;             /* overlaps reduction */    \
            const float s  = wave_sum64(p * eb);                             \
            slast = s;                                                       \
            if ((j) * CH + i == nwarm - 1)                                   \
                warmcap = __log2f(s) + Eshift;                               \
            p = fmaf(e1, s, q);                                              \
        }                                                                    \
    }                                                                        \
    /* exact pow2 renorm (once per CH steps) */                              \
    {                                                                        \
        const unsigned sb = __builtin_bit_cast(unsigned, slast);             \
        const int ef = (int)(sb >> 23);          /* biased exponent */       \
        const float sc = __builtin_bit_cast(float,                           \
                             (unsigned)(254 - ef) << 23);   /* 2^-(ef-127) */\
        p *= sc;                                                             \
        slast *= sc;                                                         \
        Eshift += (float)(ef - 127);                                         \
    } } while (0)

    const int nch = (n + CH - 1) / CH;
    if (n > 0) {
        LOAD(0, 0);
        if (nch > 1) LOAD(1, 1);
        int j = 0;
        while (true) {
            if (j + 2 < nch) LOAD(2, j + 2);
            COMPUTE(0, j);
            ++j; if (j >= nch) break;
            if (j + 2 < nch) LOAD(0, j + 2);
            COMPUTE(1, j);
            ++j; if (j >= nch) break;
            if (j + 2 < nch) LOAD(1, j + 2);
            COMPUTE(2, j);
            ++j; if (j >= nch) break;
        }
    }

    float C2;
    if (c == cstar) {   // terminal: log2(sum_k P[k] * exp(beta_stop[L,k]))
        const float bl = stopB[(size_t)L * (NB * 2) + lane * 2];
        const float s  = wave_sum64(p * __expf(bl));
        C2 = __log2f(s) + Eshift - warmcap;
    } else {
        C2 = __log2f(slast) + Eshift - warmcap;
    }

    // Private slot per (b, c): every slot the reducer reads (c <= cstar(L_b))
    // is written by exactly one block in this same launch.
    if (lane == 0)
        ws[(size_t)bi * NC + c] = C2;

#undef LOADF
#undef LOADC
#undef LOAD
#undef COMPUTE
}

__global__ __launch_bounds__(64)
void hmm_reduce(const float* __restrict__ ws,       // (B, NC) chunk C2 (log2)
                const int*   __restrict__ lengths,  // (B,)
                float* __restrict__ out, int B, int NC)
{
    const int lane = threadIdx.x;
    float acc = 0.0f;
    for (int b = lane; b < B; b += 64) {
        const int L = lengths[b];
        const int cs = (L >= 2) ? ((L - 2) / CLEN) : 0;
        float s = 0.0f;
        for (int c = 0; c <= cs; ++c)
            s += ws[(size_t)b * NC + c];
        acc += s;
    }
    const float tot = wave_sum64(acc);
    if (lane == 0)
        out[0] = -0.69314718055994531f * tot;
}

extern "C" void kernel_launch(void* const* d_in, const int* in_sizes, int n_in,
                              void* d_out, int out_size, void* d_ws, size_t ws_size,
                              hipStream_t stream)
{
    const float* stop    = (const float*)d_in[0];
    const float* start   = (const float*)d_in[1];
    const float* act     = (const float*)d_in[2];
    const int*   actions = (const int*)d_in[3];
    const int*   lengths = (const int*)d_in[4];
    float* out = (float*)d_out;
    float* ws  = (float*)d_ws;

    const int B   = in_sizes[4];
    const int T   = in_sizes[3] / B;
    const int Tp1 = T + 1;
    const int A   = in_sizes[2] / (B * Tp1 * 64);

    int NC = (T - 1 + CLEN - 1) / CLEN;   // chunks covering t=1..T-1
    if (NC < 1) NC = 1;

    hmm_fwd<<<dim3(B, NC), dim3(64), 0, stream>>>(
        stop, start, act, actions, lengths, ws, T, A, NC);
    hmm_reduce<<<dim3(1), dim3(64), 0, stream>>>(ws, lengths, out, B, NC);
}